// Round 3
// baseline (305.371 us; speedup 1.0000x reference)
//
#include <hip/hip_runtime.h>

#define N_NODES 100000
#define N_EDGES 1600000
#define DIM 128

#define NBUCK 49      // dst >> 11 -> 49 buckets of 2048 nodes
#define PCHUNK 4096   // edges per k_part block

typedef short s16x8 __attribute__((ext_vector_type(8)));
typedef float f32x4 __attribute__((ext_vector_type(4)));

__device__ __forceinline__ unsigned short f2bf(float f) {
    unsigned u = __float_as_uint(f);
    u += 0x7fffu + ((u >> 16) & 1u);   // RNE
    return (unsigned short)(u >> 16);
}
__device__ __forceinline__ float bflo(unsigned u) { return __uint_as_float(u << 16); }
__device__ __forceinline__ float bfhi(unsigned u) { return __uint_as_float(u & 0xffff0000u); }

// ---------------- CSR build ----------------

__global__ void k_zero_cnt(int* __restrict__ cnt) {
    int i = blockIdx.x * blockDim.x + threadIdx.x;
    if (i < N_NODES) cnt[i] = 0;
}

__global__ void k_count(const int* __restrict__ dst, int* __restrict__ cnt) {
    int e = blockIdx.x * blockDim.x + threadIdx.x;
    if (e < N_EDGES) atomicAdd(&cnt[dst[e]], 1);
}

__global__ void k_dinv(const int* __restrict__ cnt, float* __restrict__ dinv) {
    int i = blockIdx.x * blockDim.x + threadIdx.x;
    if (i < N_NODES) dinv[i] = rsqrtf((float)(cnt[i] + 1));  // +1 self loop
}

__global__ void k_scan_reduce(const int* __restrict__ cnt, int* __restrict__ bsum) {
    __shared__ int sm[1024];
    int t = threadIdx.x;
    int i = blockIdx.x * 1024 + t;
    sm[t] = (i < N_NODES) ? cnt[i] : 0;
    __syncthreads();
    for (int s = 512; s > 0; s >>= 1) {
        if (t < s) sm[t] += sm[t + s];
        __syncthreads();
    }
    if (t == 0) bsum[blockIdx.x] = sm[0];
}

__global__ void k_scan_bsum(int* __restrict__ bsum, int nb) {
    __shared__ int sm[128];
    int t = threadIdx.x;
    int v0 = (t < nb) ? bsum[t] : 0;
    sm[t] = v0;
    __syncthreads();
    for (int s = 1; s < 128; s <<= 1) {
        int v = (t >= s) ? sm[t - s] : 0;
        __syncthreads();
        sm[t] += v;
        __syncthreads();
    }
    if (t < nb) bsum[t] = sm[t] - v0;  // exclusive
}

__global__ void k_scan_apply(const int* __restrict__ cnt, const int* __restrict__ bsum,
                             int* __restrict__ rp, int* __restrict__ nxt) {
    __shared__ int sm[1024];
    int t = threadIdx.x;
    int i = blockIdx.x * 1024 + t;
    int v0 = (i < N_NODES) ? cnt[i] : 0;
    sm[t] = v0;
    __syncthreads();
    for (int s = 1; s < 1024; s <<= 1) {
        int v = (t >= s) ? sm[t - s] : 0;
        __syncthreads();
        sm[t] += v;
        __syncthreads();
    }
    if (i < N_NODES) {
        int excl = sm[t] - v0 + bsum[blockIdx.x];
        rp[i] = excl;
        nxt[i] = excl;
    }
}

// bucket cursor init: bucket b's ebuf/csr region starts at rp[b*2048]
__global__ void k_binit(const int* __restrict__ rp, int* __restrict__ gcur) {
    int b = threadIdx.x;
    if (b < NBUCK) gcur[b] = rp[b << 11];
}

// partition edges into dst-buckets (bucket-contiguous ebuf, L2-friendly scatter)
__global__ __launch_bounds__(256) void k_part(const int* __restrict__ src,
                                              const int* __restrict__ dst,
                                              int* __restrict__ gcur,
                                              int2* __restrict__ ebuf) {
    __shared__ int hist[NBUCK];
    __shared__ int gbase[NBUCK];
    int tid = threadIdx.x;
    long e0 = (long)blockIdx.x * PCHUNK;
    int n = min(PCHUNK, (int)(N_EDGES - e0));
    if (tid < NBUCK) hist[tid] = 0;
    __syncthreads();

    int mys[16], myd[16];
#pragma unroll
    for (int k = 0; k < 16; ++k) {
        int idx = k * 256 + tid;
        if (idx < n) {
            mys[k] = src[e0 + idx];
            myd[k] = dst[e0 + idx];
            atomicAdd(&hist[myd[k] >> 11], 1);
        } else {
            myd[k] = -1;
        }
    }
    __syncthreads();
    if (tid < NBUCK) {
        gbase[tid] = atomicAdd(&gcur[tid], hist[tid]);
        hist[tid] = 0;  // becomes local cursor
    }
    __syncthreads();
#pragma unroll
    for (int k = 0; k < 16; ++k) {
        if (myd[k] >= 0) {
            int b = myd[k] >> 11;
            int slot = gbase[b] + atomicAdd(&hist[b], 1);
            ebuf[slot] = make_int2(mys[k], myd[k]);
        }
    }
}

// fill csrw from bucket-ordered ebuf: writes now bucket-localized -> L2 absorbs
__global__ __launch_bounds__(256) void k_fill2(const int2* __restrict__ ebuf,
                                               const float* __restrict__ dinv,
                                               int* __restrict__ nxt,
                                               int2* __restrict__ csrw) {
    long base = (long)blockIdx.x * 1024;
#pragma unroll
    for (int k = 0; k < 4; ++k) {
        long e = base + k * 256 + threadIdx.x;
        if (e < N_EDGES) {
            int2 ed = ebuf[e];
            int p = atomicAdd(&nxt[ed.y], 1);
            float w = dinv[ed.x] * dinv[ed.y];
            csrw[p] = make_int2(ed.x, __float_as_int(w));
        }
    }
}

// ---------------- GEMM: h1(bf16) = x @ W1 via bf16 MFMA ----------------

#define GTILES 1563
#define GGRID  782

__global__ __launch_bounds__(256) void k_gemm(const float* __restrict__ x,
                                              const float* __restrict__ W1,
                                              unsigned short* __restrict__ h1) {
    __shared__ uint4 WtB[2048];     // 32 KB: Wt[c][k] bf16, swizzled
    __shared__ uint4 CstB[4][256];  // 4 KB per wave C-staging
    unsigned short* Wt = (unsigned short*)WtB;
    int tid = threadIdx.x;
    for (int idx = tid; idx < DIM * DIM; idx += 256) {
        int k = idx >> 7, c = idx & 127;
        Wt[c * 128 + (k ^ ((c & 7) << 3))] = f2bf(W1[idx]);
    }
    __syncthreads();

    int wv = tid >> 6, lane = tid & 63;
    int g = lane >> 4, tl = lane & 15;
    unsigned short* cst = (unsigned short*)&CstB[wv][0];

    for (int tile = blockIdx.x; tile < GTILES; tile += GGRID) {
        int rb = tile * 64 + wv * 16;
        if (rb >= N_NODES) continue;

        s16x8 afrag[4];
        const float* xrow = x + (size_t)(rb + tl) * DIM + g * 8;
#pragma unroll
        for (int kc = 0; kc < 4; ++kc) {
            float4 p0 = *(const float4*)(xrow + kc * 32);
            float4 p1 = *(const float4*)(xrow + kc * 32 + 4);
            s16x8 a;
            a[0] = (short)f2bf(p0.x); a[1] = (short)f2bf(p0.y);
            a[2] = (short)f2bf(p0.z); a[3] = (short)f2bf(p0.w);
            a[4] = (short)f2bf(p1.x); a[5] = (short)f2bf(p1.y);
            a[6] = (short)f2bf(p1.z); a[7] = (short)f2bf(p1.w);
            afrag[kc] = a;
        }

        f32x4 acc[8];
#pragma unroll
        for (int ct = 0; ct < 8; ++ct) acc[ct] = (f32x4)0.0f;
#pragma unroll
        for (int kc = 0; kc < 4; ++kc) {
#pragma unroll
            for (int ct = 0; ct < 8; ++ct) {
                int crow = ct * 16 + tl;
                int boff = crow * 256 + ((kc * 64 + g * 16) ^ ((crow & 7) << 4));
                s16x8 b = *(const s16x8*)((const char*)Wt + boff);
                acc[ct] = __builtin_amdgcn_mfma_f32_16x16x32_bf16(afrag[kc], b, acc[ct], 0, 0, 0);
            }
        }

#pragma unroll
        for (int ct = 0; ct < 8; ++ct) {
#pragma unroll
            for (int r = 0; r < 4; ++r) {
                float own = acc[ct][r];
                float oth = __shfl_xor(own, 1, 64);
                if ((lane & 1) == 0) {
                    unsigned pk = (unsigned)f2bf(own) | ((unsigned)f2bf(oth) << 16);
                    int row = g * 4 + r;
                    int col = ct * 16 + tl;
                    *(unsigned*)&cst[row * 128 + (col ^ (row << 3))] = pk;
                }
            }
        }
        asm volatile("s_waitcnt lgkmcnt(0)" ::: "memory");

        unsigned short* dstp = h1 + (size_t)rb * DIM;
#pragma unroll
        for (int c = 0; c < 4; ++c) {
            int row = c * 4 + g;
            uint4 v = *(const uint4*)&cst[row * 128 + ((tl ^ row) * 8)];
            *(uint4*)(dstp + c * 512 + lane * 8) = v;
        }
    }
}

// ---------------- agg1 + b1 + ReLU + (r @ W2) -> z[N] ----------------

__global__ __launch_bounds__(256) void k_agg1(const unsigned short* __restrict__ h1,
                                              const float* __restrict__ dinv,
                                              const int* __restrict__ rp,
                                              const int* __restrict__ cnt,
                                              const int2* __restrict__ csrw,
                                              const float* __restrict__ b1,
                                              const float* __restrict__ W2,
                                              float* __restrict__ z) {
    int lane = threadIdx.x & 63;
    int wv = threadIdx.x >> 6;
    int g = lane >> 4, tl = lane & 15;
    int i = blockIdx.x * 16 + wv * 4 + g;
    int c0 = tl * 8;
    float di = dinv[i];
    int beg = rp[i], end = beg + cnt[i];
    float a0 = 0.f, a1 = 0.f, a2 = 0.f, a3 = 0.f, a4 = 0.f, a5 = 0.f, a6 = 0.f, a7 = 0.f;
    const unsigned short* hbase = h1 + c0;

    int j = beg;
    for (; j + 2 <= end; j += 2) {
        int2 e0 = csrw[j];
        int2 e1 = csrw[j + 1];
        uint4 v0 = *(const uint4*)(hbase + (size_t)e0.x * DIM);
        uint4 v1 = *(const uint4*)(hbase + (size_t)e1.x * DIM);
        float w0 = __int_as_float(e0.y), w1 = __int_as_float(e1.y);
        a0 = fmaf(bflo(v0.x), w0, a0); a1 = fmaf(bfhi(v0.x), w0, a1);
        a2 = fmaf(bflo(v0.y), w0, a2); a3 = fmaf(bfhi(v0.y), w0, a3);
        a4 = fmaf(bflo(v0.z), w0, a4); a5 = fmaf(bfhi(v0.z), w0, a5);
        a6 = fmaf(bflo(v0.w), w0, a6); a7 = fmaf(bfhi(v0.w), w0, a7);
        a0 = fmaf(bflo(v1.x), w1, a0); a1 = fmaf(bfhi(v1.x), w1, a1);
        a2 = fmaf(bflo(v1.y), w1, a2); a3 = fmaf(bfhi(v1.y), w1, a3);
        a4 = fmaf(bflo(v1.z), w1, a4); a5 = fmaf(bfhi(v1.z), w1, a5);
        a6 = fmaf(bflo(v1.w), w1, a6); a7 = fmaf(bfhi(v1.w), w1, a7);
    }
    if (j < end) {
        int2 e0 = csrw[j];
        uint4 v0 = *(const uint4*)(hbase + (size_t)e0.x * DIM);
        float w0 = __int_as_float(e0.y);
        a0 = fmaf(bflo(v0.x), w0, a0); a1 = fmaf(bfhi(v0.x), w0, a1);
        a2 = fmaf(bflo(v0.y), w0, a2); a3 = fmaf(bfhi(v0.y), w0, a3);
        a4 = fmaf(bflo(v0.z), w0, a4); a5 = fmaf(bfhi(v0.z), w0, a5);
        a6 = fmaf(bflo(v0.w), w0, a6); a7 = fmaf(bfhi(v0.w), w0, a7);
    }

    uint4 vs = *(const uint4*)(hbase + (size_t)i * DIM);
    float sii = di * di;
    float4 bA = *(const float4*)(b1 + c0);
    float4 bB = *(const float4*)(b1 + c0 + 4);
    float4 wA = *(const float4*)(W2 + c0);
    float4 wB = *(const float4*)(W2 + c0 + 4);
    float p = 0.f;
    p += fmaxf(fmaf(bflo(vs.x), sii, a0) + bA.x, 0.f) * wA.x;
    p += fmaxf(fmaf(bfhi(vs.x), sii, a1) + bA.y, 0.f) * wA.y;
    p += fmaxf(fmaf(bflo(vs.y), sii, a2) + bA.z, 0.f) * wA.z;
    p += fmaxf(fmaf(bfhi(vs.y), sii, a3) + bA.w, 0.f) * wA.w;
    p += fmaxf(fmaf(bflo(vs.z), sii, a4) + bB.x, 0.f) * wB.x;
    p += fmaxf(fmaf(bfhi(vs.z), sii, a5) + bB.y, 0.f) * wB.y;
    p += fmaxf(fmaf(bflo(vs.w), sii, a6) + bB.z, 0.f) * wB.z;
    p += fmaxf(fmaf(bfhi(vs.w), sii, a7) + bB.w, 0.f) * wB.w;
#pragma unroll
    for (int off = 8; off >= 1; off >>= 1) p += __shfl_xor(p, off, 64);
    if (tl == 0) z[i] = p;  // b2 added in agg2
}

// ---------------- agg2 ----------------

__global__ __launch_bounds__(256) void k_agg2(const float* __restrict__ zin,
                                              const float* __restrict__ dinv,
                                              const int* __restrict__ rp,
                                              const int* __restrict__ cnt,
                                              const int2* __restrict__ csrw,
                                              const float* __restrict__ b2,
                                              float* __restrict__ out) {
    int i = blockIdx.x * blockDim.x + threadIdx.x;
    if (i >= N_NODES) return;
    float di = dinv[i];
    int beg = rp[i], end = beg + cnt[i];
    float acc = 0.f;
    int j = beg;
    for (; j + 4 <= end; j += 4) {
        int2 e0 = csrw[j], e1 = csrw[j + 1], e2 = csrw[j + 2], e3 = csrw[j + 3];
        float z0 = zin[e0.x], z1 = zin[e1.x], z2 = zin[e2.x], z3 = zin[e3.x];
        acc = fmaf(z0, __int_as_float(e0.y), acc);
        acc = fmaf(z1, __int_as_float(e1.y), acc);
        acc = fmaf(z2, __int_as_float(e2.y), acc);
        acc = fmaf(z3, __int_as_float(e3.y), acc);
    }
    for (; j < end; ++j) {
        int2 e = csrw[j];
        acc = fmaf(zin[e.x], __int_as_float(e.y), acc);
    }
    out[i] = acc + zin[i] * di * di + b2[0];
}

// ---------------- launch ----------------

extern "C" void kernel_launch(void* const* d_in, const int* in_sizes, int n_in,
                              void* d_out, int out_size, void* d_ws, size_t ws_size,
                              hipStream_t stream) {
    const float* x  = (const float*)d_in[0];
    const int*   ei = (const int*)d_in[1];
    const float* W1 = (const float*)d_in[2];
    const float* b1 = (const float*)d_in[3];
    const float* W2 = (const float*)d_in[4];
    const float* b2 = (const float*)d_in[5];
    float* out = (float*)d_out;

    const int* src = ei;
    const int* dst = ei + N_EDGES;

    char* ws = (char*)d_ws;
    size_t o = 0;
    auto take = [&](size_t bytes) { char* p = ws + o; o += (bytes + 255) & ~(size_t)255; return p; };
    int*   cnt  = (int*)take(sizeof(int) * N_NODES);
    int*   rp   = (int*)take(sizeof(int) * N_NODES);
    int*   nxt  = (int*)take(sizeof(int) * N_NODES);
    int*   bsum = (int*)take(sizeof(int) * 128);
    int*   gcur = (int*)take(sizeof(int) * 64);
    float* dinv = (float*)take(sizeof(float) * N_NODES);
    float* z    = (float*)take(sizeof(float) * N_NODES);
    int2*  csrw = (int2*)take(sizeof(int2) * N_EDGES);
    unsigned short* h1 = (unsigned short*)take(sizeof(unsigned short) * (size_t)N_NODES * DIM);
    int2*  ebuf = (int2*)h1;  // alias: ebuf (12.8MB) dead before k_gemm writes h1 (25.6MB)

    const int NB_N = (N_NODES + 255) / 256;
    const int NB_E = (N_EDGES + 255) / 256;
    const int NB_SCAN = (N_NODES + 1023) / 1024;  // 98
    const int NB_PART = (N_EDGES + PCHUNK - 1) / PCHUNK;  // 391

    k_zero_cnt<<<NB_N, 256, 0, stream>>>(cnt);
    k_count<<<NB_E, 256, 0, stream>>>(dst, cnt);
    k_dinv<<<NB_N, 256, 0, stream>>>(cnt, dinv);
    k_scan_reduce<<<NB_SCAN, 1024, 0, stream>>>(cnt, bsum);
    k_scan_bsum<<<1, 128, 0, stream>>>(bsum, NB_SCAN);
    k_scan_apply<<<NB_SCAN, 1024, 0, stream>>>(cnt, bsum, rp, nxt);
    k_binit<<<1, 64, 0, stream>>>(rp, gcur);
    k_part<<<NB_PART, 256, 0, stream>>>(src, dst, gcur, ebuf);
    k_fill2<<<(N_EDGES + 1023) / 1024, 256, 0, stream>>>(ebuf, dinv, nxt, csrw);
    k_gemm<<<GGRID, 256, 0, stream>>>(x, W1, h1);
    k_agg1<<<N_NODES / 16, 256, 0, stream>>>(h1, dinv, rp, cnt, csrw, b1, W2, z);
    k_agg2<<<NB_N, 256, 0, stream>>>(z, dinv, rp, cnt, csrw, b2, out);
}

// Round 4
// 269.599 us; speedup vs baseline: 1.1327x; 1.1327x over previous
//
#include <hip/hip_runtime.h>

#define N_NODES 100000
#define N_EDGES 1600000
#define DIM 128

#define NBUCK 49      // dst >> 11 -> 49 buckets of 2048 nodes
#define BSHIFT 11
#define BNODES 2048
#define PCHUNK 4096   // edges per k_part block

typedef short s16x8 __attribute__((ext_vector_type(8)));
typedef float f32x4 __attribute__((ext_vector_type(4)));

__device__ __forceinline__ unsigned short f2bf(float f) {
    unsigned u = __float_as_uint(f);
    u += 0x7fffu + ((u >> 16) & 1u);   // RNE
    return (unsigned short)(u >> 16);
}
__device__ __forceinline__ float bflo(unsigned u) { return __uint_as_float(u << 16); }
__device__ __forceinline__ float bfhi(unsigned u) { return __uint_as_float(u & 0xffff0000u); }

// ---------------- CSR build ----------------

__global__ void k_zero_cnt(int* __restrict__ cnt) {
    int i = blockIdx.x * blockDim.x + threadIdx.x;
    if (i < N_NODES) cnt[i] = 0;
}

__global__ void k_count(const int* __restrict__ dst, int* __restrict__ cnt) {
    int e = blockIdx.x * blockDim.x + threadIdx.x;
    if (e < N_EDGES) atomicAdd(&cnt[dst[e]], 1);
}

__global__ void k_dinv(const int* __restrict__ cnt, float* __restrict__ dinv) {
    int i = blockIdx.x * blockDim.x + threadIdx.x;
    if (i < N_NODES) dinv[i] = rsqrtf((float)(cnt[i] + 1));  // +1 self loop
}

__global__ void k_scan_reduce(const int* __restrict__ cnt, int* __restrict__ bsum) {
    __shared__ int sm[1024];
    int t = threadIdx.x;
    int i = blockIdx.x * 1024 + t;
    sm[t] = (i < N_NODES) ? cnt[i] : 0;
    __syncthreads();
    for (int s = 512; s > 0; s >>= 1) {
        if (t < s) sm[t] += sm[t + s];
        __syncthreads();
    }
    if (t == 0) bsum[blockIdx.x] = sm[0];
}

__global__ void k_scan_bsum(int* __restrict__ bsum, int nb) {
    __shared__ int sm[128];
    int t = threadIdx.x;
    int v0 = (t < nb) ? bsum[t] : 0;
    sm[t] = v0;
    __syncthreads();
    for (int s = 1; s < 128; s <<= 1) {
        int v = (t >= s) ? sm[t - s] : 0;
        __syncthreads();
        sm[t] += v;
        __syncthreads();
    }
    if (t < nb) bsum[t] = sm[t] - v0;  // exclusive
}

__global__ void k_scan_apply(const int* __restrict__ cnt, const int* __restrict__ bsum,
                             int* __restrict__ rp) {
    __shared__ int sm[1024];
    int t = threadIdx.x;
    int i = blockIdx.x * 1024 + t;
    int v0 = (i < N_NODES) ? cnt[i] : 0;
    sm[t] = v0;
    __syncthreads();
    for (int s = 1; s < 1024; s <<= 1) {
        int v = (t >= s) ? sm[t - s] : 0;
        __syncthreads();
        sm[t] += v;
        __syncthreads();
    }
    if (i < N_NODES) rp[i] = sm[t] - v0 + bsum[blockIdx.x];
}

// bucket cursor init: bucket b's ebuf region starts at rp[b*2048]
__global__ void k_binit(const int* __restrict__ rp, int* __restrict__ gcur) {
    int b = threadIdx.x;
    if (b < NBUCK) gcur[b] = rp[b << BSHIFT];
}

// partition edges into dst-buckets (per-block contiguous runs -> L2-coalesced)
__global__ __launch_bounds__(256) void k_part(const int* __restrict__ src,
                                              const int* __restrict__ dst,
                                              int* __restrict__ gcur,
                                              int2* __restrict__ ebuf) {
    __shared__ int hist[NBUCK];
    __shared__ int gbase[NBUCK];
    int tid = threadIdx.x;
    long e0 = (long)blockIdx.x * PCHUNK;
    int n = min(PCHUNK, (int)(N_EDGES - e0));
    if (tid < NBUCK) hist[tid] = 0;
    __syncthreads();

    int mys[16], myd[16];
#pragma unroll
    for (int k = 0; k < 16; ++k) {
        int idx = k * 256 + tid;
        if (idx < n) {
            mys[k] = src[e0 + idx];
            myd[k] = dst[e0 + idx];
            atomicAdd(&hist[myd[k] >> BSHIFT], 1);
        } else {
            myd[k] = -1;
        }
    }
    __syncthreads();
    if (tid < NBUCK) {
        gbase[tid] = atomicAdd(&gcur[tid], hist[tid]);
        hist[tid] = 0;  // becomes local cursor
    }
    __syncthreads();
#pragma unroll
    for (int k = 0; k < 16; ++k) {
        if (myd[k] >= 0) {
            int b = myd[k] >> BSHIFT;
            int slot = gbase[b] + atomicAdd(&hist[b], 1);
            ebuf[slot] = make_int2(mys[k], myd[k]);
        }
    }
}

// CSR emit: one block per bucket, LDS cursors; every csrw line written by
// exactly one block (one XCD) within one lifetime -> no write amplification.
__global__ __launch_bounds__(1024) void k_csr(const int2* __restrict__ ebuf,
                                              const float* __restrict__ dinv,
                                              const int* __restrict__ rp,
                                              int2* __restrict__ csrw) {
    __shared__ int lcur[BNODES];
    __shared__ float ldv[BNODES];
    int b = blockIdx.x;
    int node0 = b << BSHIFT;
    int nn = min(BNODES, N_NODES - node0);
    int base = rp[node0];
    int end = (node0 + BNODES >= N_NODES) ? N_EDGES : rp[node0 + BNODES];
    for (int t = threadIdx.x; t < nn; t += 1024) {
        lcur[t] = rp[node0 + t] - base;
        ldv[t] = dinv[node0 + t];
    }
    __syncthreads();
    int e = base + threadIdx.x;
    for (; e + 1024 < end; e += 2048) {
        int2 d0 = ebuf[e];
        int2 d1 = ebuf[e + 1024];
        int l0 = d0.y - node0, l1 = d1.y - node0;
        float w0 = dinv[d0.x] * ldv[l0];
        float w1 = dinv[d1.x] * ldv[l1];
        int p0 = atomicAdd(&lcur[l0], 1);
        int p1 = atomicAdd(&lcur[l1], 1);
        csrw[base + p0] = make_int2(d0.x, __float_as_int(w0));
        csrw[base + p1] = make_int2(d1.x, __float_as_int(w1));
    }
    if (e < end) {
        int2 d0 = ebuf[e];
        int l0 = d0.y - node0;
        float w0 = dinv[d0.x] * ldv[l0];
        int p0 = atomicAdd(&lcur[l0], 1);
        csrw[base + p0] = make_int2(d0.x, __float_as_int(w0));
    }
}

// ---------------- GEMM: h1(bf16) = x @ W1 via bf16 MFMA ----------------

#define GTILES 1563
#define GGRID  782

__global__ __launch_bounds__(256) void k_gemm(const float* __restrict__ x,
                                              const float* __restrict__ W1,
                                              unsigned short* __restrict__ h1) {
    __shared__ uint4 WtB[2048];     // 32 KB: Wt[c][k] bf16, swizzled
    __shared__ uint4 CstB[4][256];  // 4 KB per wave C-staging
    unsigned short* Wt = (unsigned short*)WtB;
    int tid = threadIdx.x;
    for (int idx = tid; idx < DIM * DIM; idx += 256) {
        int k = idx >> 7, c = idx & 127;
        Wt[c * 128 + (k ^ ((c & 7) << 3))] = f2bf(W1[idx]);
    }
    __syncthreads();

    int wv = tid >> 6, lane = tid & 63;
    int g = lane >> 4, tl = lane & 15;
    unsigned short* cst = (unsigned short*)&CstB[wv][0];

    for (int tile = blockIdx.x; tile < GTILES; tile += GGRID) {
        int rb = tile * 64 + wv * 16;
        if (rb >= N_NODES) continue;

        s16x8 afrag[4];
        const float* xrow = x + (size_t)(rb + tl) * DIM + g * 8;
#pragma unroll
        for (int kc = 0; kc < 4; ++kc) {
            float4 p0 = *(const float4*)(xrow + kc * 32);
            float4 p1 = *(const float4*)(xrow + kc * 32 + 4);
            s16x8 a;
            a[0] = (short)f2bf(p0.x); a[1] = (short)f2bf(p0.y);
            a[2] = (short)f2bf(p0.z); a[3] = (short)f2bf(p0.w);
            a[4] = (short)f2bf(p1.x); a[5] = (short)f2bf(p1.y);
            a[6] = (short)f2bf(p1.z); a[7] = (short)f2bf(p1.w);
            afrag[kc] = a;
        }

        f32x4 acc[8];
#pragma unroll
        for (int ct = 0; ct < 8; ++ct) acc[ct] = (f32x4)0.0f;
#pragma unroll
        for (int kc = 0; kc < 4; ++kc) {
#pragma unroll
            for (int ct = 0; ct < 8; ++ct) {
                int crow = ct * 16 + tl;
                int boff = crow * 256 + ((kc * 64 + g * 16) ^ ((crow & 7) << 4));
                s16x8 b = *(const s16x8*)((const char*)Wt + boff);
                acc[ct] = __builtin_amdgcn_mfma_f32_16x16x32_bf16(afrag[kc], b, acc[ct], 0, 0, 0);
            }
        }

#pragma unroll
        for (int ct = 0; ct < 8; ++ct) {
#pragma unroll
            for (int r = 0; r < 4; ++r) {
                float own = acc[ct][r];
                float oth = __shfl_xor(own, 1, 64);
                if ((lane & 1) == 0) {
                    unsigned pk = (unsigned)f2bf(own) | ((unsigned)f2bf(oth) << 16);
                    int row = g * 4 + r;
                    int col = ct * 16 + tl;
                    *(unsigned*)&cst[row * 128 + (col ^ (row << 3))] = pk;
                }
            }
        }
        asm volatile("s_waitcnt lgkmcnt(0)" ::: "memory");

        unsigned short* dstp = h1 + (size_t)rb * DIM;
#pragma unroll
        for (int c = 0; c < 4; ++c) {
            int row = c * 4 + g;
            uint4 v = *(const uint4*)&cst[row * 128 + ((tl ^ row) * 8)];
            *(uint4*)(dstp + c * 512 + lane * 8) = v;
        }
    }
}

// ---------------- agg1 + b1 + ReLU + (r @ W2) -> z[N] ----------------

__global__ __launch_bounds__(256) void k_agg1(const unsigned short* __restrict__ h1,
                                              const float* __restrict__ dinv,
                                              const int* __restrict__ rp,
                                              const int* __restrict__ cnt,
                                              const int2* __restrict__ csrw,
                                              const float* __restrict__ b1,
                                              const float* __restrict__ W2,
                                              float* __restrict__ z) {
    int lane = threadIdx.x & 63;
    int wv = threadIdx.x >> 6;
    int g = lane >> 4, tl = lane & 15;
    int i = blockIdx.x * 16 + wv * 4 + g;
    int c0 = tl * 8;
    float di = dinv[i];
    int beg = rp[i], end = beg + cnt[i];
    float a0 = 0.f, a1 = 0.f, a2 = 0.f, a3 = 0.f, a4 = 0.f, a5 = 0.f, a6 = 0.f, a7 = 0.f;
    const unsigned short* hbase = h1 + c0;

    int j = beg;
    for (; j + 2 <= end; j += 2) {
        int2 e0 = csrw[j];
        int2 e1 = csrw[j + 1];
        uint4 v0 = *(const uint4*)(hbase + (size_t)e0.x * DIM);
        uint4 v1 = *(const uint4*)(hbase + (size_t)e1.x * DIM);
        float w0 = __int_as_float(e0.y), w1 = __int_as_float(e1.y);
        a0 = fmaf(bflo(v0.x), w0, a0); a1 = fmaf(bfhi(v0.x), w0, a1);
        a2 = fmaf(bflo(v0.y), w0, a2); a3 = fmaf(bfhi(v0.y), w0, a3);
        a4 = fmaf(bflo(v0.z), w0, a4); a5 = fmaf(bfhi(v0.z), w0, a5);
        a6 = fmaf(bflo(v0.w), w0, a6); a7 = fmaf(bfhi(v0.w), w0, a7);
        a0 = fmaf(bflo(v1.x), w1, a0); a1 = fmaf(bfhi(v1.x), w1, a1);
        a2 = fmaf(bflo(v1.y), w1, a2); a3 = fmaf(bfhi(v1.y), w1, a3);
        a4 = fmaf(bflo(v1.z), w1, a4); a5 = fmaf(bfhi(v1.z), w1, a5);
        a6 = fmaf(bflo(v1.w), w1, a6); a7 = fmaf(bfhi(v1.w), w1, a7);
    }
    if (j < end) {
        int2 e0 = csrw[j];
        uint4 v0 = *(const uint4*)(hbase + (size_t)e0.x * DIM);
        float w0 = __int_as_float(e0.y);
        a0 = fmaf(bflo(v0.x), w0, a0); a1 = fmaf(bfhi(v0.x), w0, a1);
        a2 = fmaf(bflo(v0.y), w0, a2); a3 = fmaf(bfhi(v0.y), w0, a3);
        a4 = fmaf(bflo(v0.z), w0, a4); a5 = fmaf(bfhi(v0.z), w0, a5);
        a6 = fmaf(bflo(v0.w), w0, a6); a7 = fmaf(bfhi(v0.w), w0, a7);
    }

    uint4 vs = *(const uint4*)(hbase + (size_t)i * DIM);
    float sii = di * di;
    float4 bA = *(const float4*)(b1 + c0);
    float4 bB = *(const float4*)(b1 + c0 + 4);
    float4 wA = *(const float4*)(W2 + c0);
    float4 wB = *(const float4*)(W2 + c0 + 4);
    float p = 0.f;
    p += fmaxf(fmaf(bflo(vs.x), sii, a0) + bA.x, 0.f) * wA.x;
    p += fmaxf(fmaf(bfhi(vs.x), sii, a1) + bA.y, 0.f) * wA.y;
    p += fmaxf(fmaf(bflo(vs.y), sii, a2) + bA.z, 0.f) * wA.z;
    p += fmaxf(fmaf(bfhi(vs.y), sii, a3) + bA.w, 0.f) * wA.w;
    p += fmaxf(fmaf(bflo(vs.z), sii, a4) + bB.x, 0.f) * wB.x;
    p += fmaxf(fmaf(bfhi(vs.z), sii, a5) + bB.y, 0.f) * wB.y;
    p += fmaxf(fmaf(bflo(vs.w), sii, a6) + bB.z, 0.f) * wB.z;
    p += fmaxf(fmaf(bfhi(vs.w), sii, a7) + bB.w, 0.f) * wB.w;
#pragma unroll
    for (int off = 8; off >= 1; off >>= 1) p += __shfl_xor(p, off, 64);
    if (tl == 0) z[i] = p;  // b2 added in agg2
}

// ---------------- agg2 ----------------

__global__ __launch_bounds__(256) void k_agg2(const float* __restrict__ zin,
                                              const float* __restrict__ dinv,
                                              const int* __restrict__ rp,
                                              const int* __restrict__ cnt,
                                              const int2* __restrict__ csrw,
                                              const float* __restrict__ b2,
                                              float* __restrict__ out) {
    int i = blockIdx.x * blockDim.x + threadIdx.x;
    if (i >= N_NODES) return;
    float di = dinv[i];
    int beg = rp[i], end = beg + cnt[i];
    float acc = 0.f;
    int j = beg;
    for (; j + 4 <= end; j += 4) {
        int2 e0 = csrw[j], e1 = csrw[j + 1], e2 = csrw[j + 2], e3 = csrw[j + 3];
        float z0 = zin[e0.x], z1 = zin[e1.x], z2 = zin[e2.x], z3 = zin[e3.x];
        acc = fmaf(z0, __int_as_float(e0.y), acc);
        acc = fmaf(z1, __int_as_float(e1.y), acc);
        acc = fmaf(z2, __int_as_float(e2.y), acc);
        acc = fmaf(z3, __int_as_float(e3.y), acc);
    }
    for (; j < end; ++j) {
        int2 e = csrw[j];
        acc = fmaf(zin[e.x], __int_as_float(e.y), acc);
    }
    out[i] = acc + zin[i] * di * di + b2[0];
}

// ---------------- launch ----------------

extern "C" void kernel_launch(void* const* d_in, const int* in_sizes, int n_in,
                              void* d_out, int out_size, void* d_ws, size_t ws_size,
                              hipStream_t stream) {
    const float* x  = (const float*)d_in[0];
    const int*   ei = (const int*)d_in[1];
    const float* W1 = (const float*)d_in[2];
    const float* b1 = (const float*)d_in[3];
    const float* W2 = (const float*)d_in[4];
    const float* b2 = (const float*)d_in[5];
    float* out = (float*)d_out;

    const int* src = ei;
    const int* dst = ei + N_EDGES;

    char* ws = (char*)d_ws;
    size_t o = 0;
    auto take = [&](size_t bytes) { char* p = ws + o; o += (bytes + 255) & ~(size_t)255; return p; };
    int*   cnt  = (int*)take(sizeof(int) * N_NODES);
    int*   rp   = (int*)take(sizeof(int) * N_NODES);
    int*   bsum = (int*)take(sizeof(int) * 128);
    int*   gcur = (int*)take(sizeof(int) * 64);
    float* dinv = (float*)take(sizeof(float) * N_NODES);
    float* z    = (float*)take(sizeof(float) * N_NODES);
    int2*  csrw = (int2*)take(sizeof(int2) * N_EDGES);
    unsigned short* h1 = (unsigned short*)take(sizeof(unsigned short) * (size_t)N_NODES * DIM);
    int2*  ebuf = (int2*)h1;  // alias: ebuf (12.8MB) dead before k_gemm writes h1 (25.6MB)

    const int NB_N = (N_NODES + 255) / 256;
    const int NB_E = (N_EDGES + 255) / 256;
    const int NB_SCAN = (N_NODES + 1023) / 1024;  // 98
    const int NB_PART = (N_EDGES + PCHUNK - 1) / PCHUNK;  // 391

    k_zero_cnt<<<NB_N, 256, 0, stream>>>(cnt);
    k_count<<<NB_E, 256, 0, stream>>>(dst, cnt);
    k_dinv<<<NB_N, 256, 0, stream>>>(cnt, dinv);
    k_scan_reduce<<<NB_SCAN, 1024, 0, stream>>>(cnt, bsum);
    k_scan_bsum<<<1, 128, 0, stream>>>(bsum, NB_SCAN);
    k_scan_apply<<<NB_SCAN, 1024, 0, stream>>>(cnt, bsum, rp);
    k_binit<<<1, 64, 0, stream>>>(rp, gcur);
    k_part<<<NB_PART, 256, 0, stream>>>(src, dst, gcur, ebuf);
    k_csr<<<NBUCK, 1024, 0, stream>>>(ebuf, dinv, rp, csrw);
    k_gemm<<<GGRID, 256, 0, stream>>>(x, W1, h1);
    k_agg1<<<N_NODES / 16, 256, 0, stream>>>(h1, dinv, rp, cnt, csrw, b1, W2, z);
    k_agg2<<<NB_N, 256, 0, stream>>>(z, dinv, rp, cnt, csrw, b2, out);
}

// Round 5
// 209.595 us; speedup vs baseline: 1.4570x; 1.2863x over previous
//
#include <hip/hip_runtime.h>

#define N_NODES 100000
#define N_EDGES 1600000
#define DIM 128

#define NBUCK 49      // dst >> 11 -> 49 buckets of 2048 nodes
#define BSHIFT 11
#define BNODES 2048
#define PCHUNK 4096   // edges per k_part / k_bcount block

typedef short s16x8 __attribute__((ext_vector_type(8)));
typedef float f32x4 __attribute__((ext_vector_type(4)));

__device__ __forceinline__ unsigned short f2bf(float f) {
    unsigned u = __float_as_uint(f);
    u += 0x7fffu + ((u >> 16) & 1u);   // RNE
    return (unsigned short)(u >> 16);
}
__device__ __forceinline__ float bflo(unsigned u) { return __uint_as_float(u << 16); }
__device__ __forceinline__ float bfhi(unsigned u) { return __uint_as_float(u & 0xffff0000u); }

// ---------------- CSR build (atomic-light, bucket-local) ----------------

__global__ void k_zero(int* __restrict__ bcnt) {
    int t = threadIdx.x;
    if (t < NBUCK) bcnt[t] = 0;
}

// per-block LDS histogram over 49 buckets; 49 global atomics per block
__global__ __launch_bounds__(256) void k_bcount(const int* __restrict__ dst,
                                                int* __restrict__ bcnt) {
    __shared__ int hist[NBUCK];
    int tid = threadIdx.x;
    if (tid < NBUCK) hist[tid] = 0;
    __syncthreads();
    long e0 = (long)blockIdx.x * PCHUNK;
    int n = min(PCHUNK, (int)(N_EDGES - e0));
    for (int idx = tid; idx < n; idx += 256)
        atomicAdd(&hist[dst[e0 + idx] >> BSHIFT], 1);
    __syncthreads();
    if (tid < NBUCK) atomicAdd(&bcnt[tid], hist[tid]);
}

// single-wave shfl scan: bbase (exclusive, +sentinel) and partition cursors
__global__ void k_bscan(const int* __restrict__ bcnt, int* __restrict__ bbase,
                        int* __restrict__ gcur) {
    int t = threadIdx.x;  // one wave of 64
    int c = (t < NBUCK) ? bcnt[t] : 0;
    int v = c;
#pragma unroll
    for (int s = 1; s < 64; s <<= 1) {
        int u = __shfl_up(v, s, 64);
        if (t >= s) v += u;
    }
    int excl = v - c;   // lanes >= NBUCK: excl == total == N_EDGES
    if (t <= NBUCK) bbase[t] = excl;
    if (t < NBUCK) gcur[t] = excl;
}

// partition edges into dst-buckets (per-block contiguous runs -> L2-coalesced)
__global__ __launch_bounds__(256) void k_part(const int* __restrict__ src,
                                              const int* __restrict__ dst,
                                              int* __restrict__ gcur,
                                              int2* __restrict__ ebuf) {
    __shared__ int hist[NBUCK];
    __shared__ int gbase[NBUCK];
    int tid = threadIdx.x;
    long e0 = (long)blockIdx.x * PCHUNK;
    int n = min(PCHUNK, (int)(N_EDGES - e0));
    if (tid < NBUCK) hist[tid] = 0;
    __syncthreads();

    int mys[16], myd[16];
#pragma unroll
    for (int k = 0; k < 16; ++k) {
        int idx = k * 256 + tid;
        if (idx < n) {
            mys[k] = src[e0 + idx];
            myd[k] = dst[e0 + idx];
            atomicAdd(&hist[myd[k] >> BSHIFT], 1);
        } else {
            myd[k] = -1;
        }
    }
    __syncthreads();
    if (tid < NBUCK) {
        gbase[tid] = atomicAdd(&gcur[tid], hist[tid]);
        hist[tid] = 0;  // becomes local cursor
    }
    __syncthreads();
#pragma unroll
    for (int k = 0; k < 16; ++k) {
        if (myd[k] >= 0) {
            int b = myd[k] >> BSHIFT;
            int slot = gbase[b] + atomicAdd(&hist[b], 1);
            ebuf[slot] = make_int2(mys[k], myd[k]);
        }
    }
}

// per-bucket: LDS degree count + 2048-wide LDS scan -> rp, cnt, dinv
__global__ __launch_bounds__(1024) void k_csrA(const int2* __restrict__ ebuf,
                                               const int* __restrict__ bbase,
                                               int* __restrict__ rp,
                                               int* __restrict__ cnt,
                                               float* __restrict__ dinv) {
    __shared__ int lcnt[BNODES];
    __shared__ int psum[1024];
    int b = blockIdx.x, t = threadIdx.x;
    int node0 = b << BSHIFT;
    lcnt[t] = 0; lcnt[t + 1024] = 0;
    __syncthreads();
    int base = bbase[b], end = bbase[b + 1];
    for (int e = base + t; e < end; e += 1024)
        atomicAdd(&lcnt[ebuf[e].y - node0], 1);
    __syncthreads();
    int c0 = lcnt[2 * t], c1 = lcnt[2 * t + 1];
    int ps = c0 + c1;
    psum[t] = ps;
    __syncthreads();
    for (int s = 1; s < 1024; s <<= 1) {
        int u = (t >= s) ? psum[t - s] : 0;
        __syncthreads();
        psum[t] += u;
        __syncthreads();
    }
    int excl0 = psum[t] - ps;  // exclusive over pairs
    int n0 = node0 + 2 * t, n1 = n0 + 1;
    if (n0 < N_NODES) { rp[n0] = base + excl0; cnt[n0] = c0; dinv[n0] = rsqrtf((float)(c0 + 1)); }
    if (n1 < N_NODES) { rp[n1] = base + excl0 + c0; cnt[n1] = c1; dinv[n1] = rsqrtf((float)(c1 + 1)); }
}

// per-bucket CSR emit with LDS cursors; single-XCD, time-local writes
__global__ __launch_bounds__(1024) void k_csrB(const int2* __restrict__ ebuf,
                                               const int* __restrict__ bbase,
                                               const int* __restrict__ rp,
                                               const float* __restrict__ dinv,
                                               int2* __restrict__ csrw) {
    __shared__ int lcur[BNODES];
    __shared__ float ldv[BNODES];
    int b = blockIdx.x, t = threadIdx.x;
    int node0 = b << BSHIFT;
    int base = bbase[b], end = bbase[b + 1];
    for (int k = t; k < BNODES; k += 1024) {
        int nd = node0 + k;
        if (nd < N_NODES) { lcur[k] = rp[nd] - base; ldv[k] = dinv[nd]; }
    }
    __syncthreads();
    for (int e = base + t; e < end; e += 1024) {
        int2 d = ebuf[e];
        int l = d.y - node0;
        float w = dinv[d.x] * ldv[l];
        int p = atomicAdd(&lcur[l], 1);
        csrw[base + p] = make_int2(d.x, __float_as_int(w));
    }
}

// ---------------- GEMM: h1(bf16) = x @ W1 via bf16 MFMA ----------------

#define GTILES 1563
#define GGRID  782

__global__ __launch_bounds__(256) void k_gemm(const float* __restrict__ x,
                                              const float* __restrict__ W1,
                                              unsigned short* __restrict__ h1) {
    __shared__ uint4 WtB[2048];     // 32 KB: Wt[c][k] bf16, swizzled
    __shared__ uint4 CstB[4][256];  // 4 KB per wave C-staging
    unsigned short* Wt = (unsigned short*)WtB;
    int tid = threadIdx.x;
    for (int idx = tid; idx < DIM * DIM; idx += 256) {
        int k = idx >> 7, c = idx & 127;
        Wt[c * 128 + (k ^ ((c & 7) << 3))] = f2bf(W1[idx]);
    }
    __syncthreads();

    int wv = tid >> 6, lane = tid & 63;
    int g = lane >> 4, tl = lane & 15;
    unsigned short* cst = (unsigned short*)&CstB[wv][0];

    for (int tile = blockIdx.x; tile < GTILES; tile += GGRID) {
        int rb = tile * 64 + wv * 16;
        if (rb >= N_NODES) continue;

        s16x8 afrag[4];
        const float* xrow = x + (size_t)(rb + tl) * DIM + g * 8;
#pragma unroll
        for (int kc = 0; kc < 4; ++kc) {
            float4 p0 = *(const float4*)(xrow + kc * 32);
            float4 p1 = *(const float4*)(xrow + kc * 32 + 4);
            s16x8 a;
            a[0] = (short)f2bf(p0.x); a[1] = (short)f2bf(p0.y);
            a[2] = (short)f2bf(p0.z); a[3] = (short)f2bf(p0.w);
            a[4] = (short)f2bf(p1.x); a[5] = (short)f2bf(p1.y);
            a[6] = (short)f2bf(p1.z); a[7] = (short)f2bf(p1.w);
            afrag[kc] = a;
        }

        f32x4 acc[8];
#pragma unroll
        for (int ct = 0; ct < 8; ++ct) acc[ct] = (f32x4)0.0f;
#pragma unroll
        for (int kc = 0; kc < 4; ++kc) {
#pragma unroll
            for (int ct = 0; ct < 8; ++ct) {
                int crow = ct * 16 + tl;
                int boff = crow * 256 + ((kc * 64 + g * 16) ^ ((crow & 7) << 4));
                s16x8 b = *(const s16x8*)((const char*)Wt + boff);
                acc[ct] = __builtin_amdgcn_mfma_f32_16x16x32_bf16(afrag[kc], b, acc[ct], 0, 0, 0);
            }
        }

#pragma unroll
        for (int ct = 0; ct < 8; ++ct) {
#pragma unroll
            for (int r = 0; r < 4; ++r) {
                float own = acc[ct][r];
                float oth = __shfl_xor(own, 1, 64);
                if ((lane & 1) == 0) {
                    unsigned pk = (unsigned)f2bf(own) | ((unsigned)f2bf(oth) << 16);
                    int row = g * 4 + r;
                    int col = ct * 16 + tl;
                    *(unsigned*)&cst[row * 128 + (col ^ (row << 3))] = pk;
                }
            }
        }
        asm volatile("s_waitcnt lgkmcnt(0)" ::: "memory");

        unsigned short* dstp = h1 + (size_t)rb * DIM;
#pragma unroll
        for (int c = 0; c < 4; ++c) {
            int row = c * 4 + g;
            uint4 v = *(const uint4*)&cst[row * 128 + ((tl ^ row) * 8)];
            *(uint4*)(dstp + c * 512 + lane * 8) = v;
        }
    }
}

// ---------------- agg1 + b1 + ReLU + (r @ W2) -> z[N] ----------------

__global__ __launch_bounds__(256) void k_agg1(const unsigned short* __restrict__ h1,
                                              const float* __restrict__ dinv,
                                              const int* __restrict__ rp,
                                              const int* __restrict__ cnt,
                                              const int2* __restrict__ csrw,
                                              const float* __restrict__ b1,
                                              const float* __restrict__ W2,
                                              float* __restrict__ z) {
    int lane = threadIdx.x & 63;
    int wv = threadIdx.x >> 6;
    int g = lane >> 4, tl = lane & 15;
    int i = blockIdx.x * 16 + wv * 4 + g;
    int c0 = tl * 8;
    float di = dinv[i];
    int beg = rp[i], end = beg + cnt[i];
    float a0 = 0.f, a1 = 0.f, a2 = 0.f, a3 = 0.f, a4 = 0.f, a5 = 0.f, a6 = 0.f, a7 = 0.f;
    const unsigned short* hbase = h1 + c0;

    int j = beg;
    for (; j + 2 <= end; j += 2) {
        int2 e0 = csrw[j];
        int2 e1 = csrw[j + 1];
        uint4 v0 = *(const uint4*)(hbase + (size_t)e0.x * DIM);
        uint4 v1 = *(const uint4*)(hbase + (size_t)e1.x * DIM);
        float w0 = __int_as_float(e0.y), w1 = __int_as_float(e1.y);
        a0 = fmaf(bflo(v0.x), w0, a0); a1 = fmaf(bfhi(v0.x), w0, a1);
        a2 = fmaf(bflo(v0.y), w0, a2); a3 = fmaf(bfhi(v0.y), w0, a3);
        a4 = fmaf(bflo(v0.z), w0, a4); a5 = fmaf(bfhi(v0.z), w0, a5);
        a6 = fmaf(bflo(v0.w), w0, a6); a7 = fmaf(bfhi(v0.w), w0, a7);
        a0 = fmaf(bflo(v1.x), w1, a0); a1 = fmaf(bfhi(v1.x), w1, a1);
        a2 = fmaf(bflo(v1.y), w1, a2); a3 = fmaf(bfhi(v1.y), w1, a3);
        a4 = fmaf(bflo(v1.z), w1, a4); a5 = fmaf(bfhi(v1.z), w1, a5);
        a6 = fmaf(bflo(v1.w), w1, a6); a7 = fmaf(bfhi(v1.w), w1, a7);
    }
    if (j < end) {
        int2 e0 = csrw[j];
        uint4 v0 = *(const uint4*)(hbase + (size_t)e0.x * DIM);
        float w0 = __int_as_float(e0.y);
        a0 = fmaf(bflo(v0.x), w0, a0); a1 = fmaf(bfhi(v0.x), w0, a1);
        a2 = fmaf(bflo(v0.y), w0, a2); a3 = fmaf(bfhi(v0.y), w0, a3);
        a4 = fmaf(bflo(v0.z), w0, a4); a5 = fmaf(bfhi(v0.z), w0, a5);
        a6 = fmaf(bflo(v0.w), w0, a6); a7 = fmaf(bfhi(v0.w), w0, a7);
    }

    uint4 vs = *(const uint4*)(hbase + (size_t)i * DIM);
    float sii = di * di;
    float4 bA = *(const float4*)(b1 + c0);
    float4 bB = *(const float4*)(b1 + c0 + 4);
    float4 wA = *(const float4*)(W2 + c0);
    float4 wB = *(const float4*)(W2 + c0 + 4);
    float p = 0.f;
    p += fmaxf(fmaf(bflo(vs.x), sii, a0) + bA.x, 0.f) * wA.x;
    p += fmaxf(fmaf(bfhi(vs.x), sii, a1) + bA.y, 0.f) * wA.y;
    p += fmaxf(fmaf(bflo(vs.y), sii, a2) + bA.z, 0.f) * wA.z;
    p += fmaxf(fmaf(bfhi(vs.y), sii, a3) + bA.w, 0.f) * wA.w;
    p += fmaxf(fmaf(bflo(vs.z), sii, a4) + bB.x, 0.f) * wB.x;
    p += fmaxf(fmaf(bfhi(vs.z), sii, a5) + bB.y, 0.f) * wB.y;
    p += fmaxf(fmaf(bflo(vs.w), sii, a6) + bB.z, 0.f) * wB.z;
    p += fmaxf(fmaf(bfhi(vs.w), sii, a7) + bB.w, 0.f) * wB.w;
#pragma unroll
    for (int off = 8; off >= 1; off >>= 1) p += __shfl_xor(p, off, 64);
    if (tl == 0) z[i] = p;  // b2 added in agg2
}

// ---------------- agg2 ----------------

__global__ __launch_bounds__(256) void k_agg2(const float* __restrict__ zin,
                                              const float* __restrict__ dinv,
                                              const int* __restrict__ rp,
                                              const int* __restrict__ cnt,
                                              const int2* __restrict__ csrw,
                                              const float* __restrict__ b2,
                                              float* __restrict__ out) {
    int i = blockIdx.x * blockDim.x + threadIdx.x;
    if (i >= N_NODES) return;
    float di = dinv[i];
    int beg = rp[i], end = beg + cnt[i];
    float acc = 0.f;
    int j = beg;
    for (; j + 4 <= end; j += 4) {
        int2 e0 = csrw[j], e1 = csrw[j + 1], e2 = csrw[j + 2], e3 = csrw[j + 3];
        float z0 = zin[e0.x], z1 = zin[e1.x], z2 = zin[e2.x], z3 = zin[e3.x];
        acc = fmaf(z0, __int_as_float(e0.y), acc);
        acc = fmaf(z1, __int_as_float(e1.y), acc);
        acc = fmaf(z2, __int_as_float(e2.y), acc);
        acc = fmaf(z3, __int_as_float(e3.y), acc);
    }
    for (; j < end; ++j) {
        int2 e = csrw[j];
        acc = fmaf(zin[e.x], __int_as_float(e.y), acc);
    }
    out[i] = acc + zin[i] * di * di + b2[0];
}

// ---------------- launch ----------------

extern "C" void kernel_launch(void* const* d_in, const int* in_sizes, int n_in,
                              void* d_out, int out_size, void* d_ws, size_t ws_size,
                              hipStream_t stream) {
    const float* x  = (const float*)d_in[0];
    const int*   ei = (const int*)d_in[1];
    const float* W1 = (const float*)d_in[2];
    const float* b1 = (const float*)d_in[3];
    const float* W2 = (const float*)d_in[4];
    const float* b2 = (const float*)d_in[5];
    float* out = (float*)d_out;

    const int* src = ei;
    const int* dst = ei + N_EDGES;

    char* ws = (char*)d_ws;
    size_t o = 0;
    auto take = [&](size_t bytes) { char* p = ws + o; o += (bytes + 255) & ~(size_t)255; return p; };
    int*   cnt   = (int*)take(sizeof(int) * N_NODES);
    int*   rp    = (int*)take(sizeof(int) * N_NODES);
    int*   bcnt  = (int*)take(sizeof(int) * 64);
    int*   bbase = (int*)take(sizeof(int) * 64);
    int*   gcur  = (int*)take(sizeof(int) * 64);
    float* dinv  = (float*)take(sizeof(float) * N_NODES);
    float* z     = (float*)take(sizeof(float) * N_NODES);
    int2*  csrw  = (int2*)take(sizeof(int2) * N_EDGES);
    unsigned short* h1 = (unsigned short*)take(sizeof(unsigned short) * (size_t)N_NODES * DIM);
    int2*  ebuf  = (int2*)h1;  // alias: ebuf (12.8MB) dead before k_gemm writes h1 (25.6MB)

    const int NB_N = (N_NODES + 255) / 256;
    const int NB_PART = (N_EDGES + PCHUNK - 1) / PCHUNK;  // 391

    k_zero<<<1, 64, 0, stream>>>(bcnt);
    k_bcount<<<NB_PART, 256, 0, stream>>>(dst, bcnt);
    k_bscan<<<1, 64, 0, stream>>>(bcnt, bbase, gcur);
    k_part<<<NB_PART, 256, 0, stream>>>(src, dst, gcur, ebuf);
    k_csrA<<<NBUCK, 1024, 0, stream>>>(ebuf, bbase, rp, cnt, dinv);
    k_csrB<<<NBUCK, 1024, 0, stream>>>(ebuf, bbase, rp, dinv, csrw);
    k_gemm<<<GGRID, 256, 0, stream>>>(x, W1, h1);
    k_agg1<<<N_NODES / 16, 256, 0, stream>>>(h1, dinv, rp, cnt, csrw, b1, W2, z);
    k_agg2<<<NB_N, 256, 0, stream>>>(z, dinv, rp, cnt, csrw, b2, out);
}

// Round 6
// 162.675 us; speedup vs baseline: 1.8772x; 1.2884x over previous
//
#include <hip/hip_runtime.h>

#define N_NODES 100000
#define N_EDGES 1600000
#define DIM 128

#define BSHIFT 8
#define BNODES 256
#define NBUCK 391     // ceil(100000/256)
#define PCHUNK 4096   // edges per part/bcount block
#define NB_PART ((N_EDGES + PCHUNK - 1) / PCHUNK)  // 391

#define GTILES 1563   // ceil(100000/64)
#define GGRID  782

typedef short s16x8 __attribute__((ext_vector_type(8)));
typedef float f32x4 __attribute__((ext_vector_type(4)));

__device__ __forceinline__ unsigned short f2bf(float f) {
    unsigned u = __float_as_uint(f);
    u += 0x7fffu + ((u >> 16) & 1u);   // RNE
    return (unsigned short)(u >> 16);
}
__device__ __forceinline__ float bflo(unsigned u) { return __uint_as_float(u << 16); }
__device__ __forceinline__ float bfhi(unsigned u) { return __uint_as_float(u & 0xffff0000u); }

// ---------------- CSR build ----------------

__global__ void k_zero(int* __restrict__ bcnt) {
    int t = blockIdx.x * blockDim.x + threadIdx.x;
    if (t < NBUCK) bcnt[t] = 0;
}

__global__ __launch_bounds__(256) void k_bcount(const int* __restrict__ dst,
                                                int* __restrict__ bcnt) {
    __shared__ int hist[NBUCK];
    int tid = threadIdx.x;
    for (int b = tid; b < NBUCK; b += 256) hist[b] = 0;
    __syncthreads();
    long e0 = (long)blockIdx.x * PCHUNK;
    int n = min(PCHUNK, (int)(N_EDGES - e0));
    for (int idx = tid; idx < n; idx += 256)
        atomicAdd(&hist[dst[e0 + idx] >> BSHIFT], 1);
    __syncthreads();
    for (int b = tid; b < NBUCK; b += 256)
        if (hist[b]) atomicAdd(&bcnt[b], hist[b]);
}

// one block, 512 threads: exclusive scan of 391 bucket counts
__global__ __launch_bounds__(512) void k_bscan(const int* __restrict__ bcnt,
                                               int* __restrict__ bbase,
                                               int* __restrict__ gcur) {
    __shared__ int sm[512];
    int t = threadIdx.x;
    int c = (t < NBUCK) ? bcnt[t] : 0;
    sm[t] = c;
    __syncthreads();
    for (int s = 1; s < 512; s <<= 1) {
        int u = (t >= s) ? sm[t - s] : 0;
        __syncthreads();
        sm[t] += u;
        __syncthreads();
    }
    int excl = sm[t] - c;
    if (t < NBUCK) { bbase[t] = excl; gcur[t] = excl; }
    if (t == NBUCK) bbase[t] = excl;  // == N_EDGES
}

// ---- partition body (shared by standalone + fused kernels) ----
__device__ __forceinline__ void part_body(char* smem, int bid,
                                          const int* __restrict__ src,
                                          const int* __restrict__ dst,
                                          int* __restrict__ gcur,
                                          int2* __restrict__ ebuf) {
    int* hist = (int*)smem;
    int* gbase = hist + NBUCK;
    int tid = threadIdx.x;
    long e0 = (long)bid * PCHUNK;
    int n = min(PCHUNK, (int)(N_EDGES - e0));
    for (int b = tid; b < NBUCK; b += 256) hist[b] = 0;
    __syncthreads();

    int mys[16], myd[16];
#pragma unroll
    for (int k = 0; k < 16; ++k) {
        int idx = k * 256 + tid;
        if (idx < n) {
            mys[k] = src[e0 + idx];
            myd[k] = dst[e0 + idx];
            atomicAdd(&hist[myd[k] >> BSHIFT], 1);
        } else {
            myd[k] = -1;
        }
    }
    __syncthreads();
    for (int b = tid; b < NBUCK; b += 256) {
        gbase[b] = hist[b] ? atomicAdd(&gcur[b], hist[b]) : 0;
        hist[b] = 0;  // becomes local cursor
    }
    __syncthreads();
#pragma unroll
    for (int k = 0; k < 16; ++k) {
        if (myd[k] >= 0) {
            int b = myd[k] >> BSHIFT;
            int slot = gbase[b] + atomicAdd(&hist[b], 1);
            ebuf[slot] = make_int2(mys[k], myd[k]);
        }
    }
}

// ---- GEMM body: h1(bf16) = x @ W1, bf16 MFMA, swizzled LDS ----
__device__ __forceinline__ void gemm_body(char* smem, int bid,
                                          const float* __restrict__ x,
                                          const float* __restrict__ W1,
                                          unsigned short* __restrict__ h1) {
    unsigned short* Wt = (unsigned short*)smem;           // 32 KB
    int tid = threadIdx.x;
    for (int idx = tid; idx < DIM * DIM; idx += 256) {
        int k = idx >> 7, c = idx & 127;
        Wt[c * 128 + (k ^ ((c & 7) << 3))] = f2bf(W1[idx]);
    }
    __syncthreads();

    int wv = tid >> 6, lane = tid & 63;
    int g = lane >> 4, tl = lane & 15;
    unsigned short* cst = (unsigned short*)(smem + 32768 + wv * 4096);

    for (int tile = bid; tile < GTILES; tile += GGRID) {
        int rb = tile * 64 + wv * 16;
        if (rb >= N_NODES) continue;

        s16x8 afrag[4];
        const float* xrow = x + (size_t)(rb + tl) * DIM + g * 8;
#pragma unroll
        for (int kc = 0; kc < 4; ++kc) {
            float4 p0 = *(const float4*)(xrow + kc * 32);
            float4 p1 = *(const float4*)(xrow + kc * 32 + 4);
            s16x8 a;
            a[0] = (short)f2bf(p0.x); a[1] = (short)f2bf(p0.y);
            a[2] = (short)f2bf(p0.z); a[3] = (short)f2bf(p0.w);
            a[4] = (short)f2bf(p1.x); a[5] = (short)f2bf(p1.y);
            a[6] = (short)f2bf(p1.z); a[7] = (short)f2bf(p1.w);
            afrag[kc] = a;
        }

        f32x4 acc[8];
#pragma unroll
        for (int ct = 0; ct < 8; ++ct) acc[ct] = (f32x4)0.0f;
#pragma unroll
        for (int kc = 0; kc < 4; ++kc) {
#pragma unroll
            for (int ct = 0; ct < 8; ++ct) {
                int crow = ct * 16 + tl;
                int boff = crow * 256 + ((kc * 64 + g * 16) ^ ((crow & 7) << 4));
                s16x8 b = *(const s16x8*)((const char*)Wt + boff);
                acc[ct] = __builtin_amdgcn_mfma_f32_16x16x32_bf16(afrag[kc], b, acc[ct], 0, 0, 0);
            }
        }

#pragma unroll
        for (int ct = 0; ct < 8; ++ct) {
#pragma unroll
            for (int r = 0; r < 4; ++r) {
                float own = acc[ct][r];
                float oth = __shfl_xor(own, 1, 64);
                if ((lane & 1) == 0) {
                    unsigned pk = (unsigned)f2bf(own) | ((unsigned)f2bf(oth) << 16);
                    int row = g * 4 + r;
                    int col = ct * 16 + tl;
                    *(unsigned*)&cst[row * 128 + (col ^ (row << 3))] = pk;
                }
            }
        }
        asm volatile("s_waitcnt lgkmcnt(0)" ::: "memory");

        unsigned short* dstp = h1 + (size_t)rb * DIM;
#pragma unroll
        for (int c = 0; c < 4; ++c) {
            int row = c * 4 + g;
            uint4 v = *(const uint4*)&cst[row * 128 + ((tl ^ row) * 8)];
            *(uint4*)(dstp + c * 512 + lane * 8) = v;
        }
    }
}

// standalone kernels (fallback path when ws is tight)
__global__ __launch_bounds__(256) void k_part(const int* __restrict__ src,
                                              const int* __restrict__ dst,
                                              int* __restrict__ gcur,
                                              int2* __restrict__ ebuf) {
    __shared__ __align__(16) char smem[2 * NBUCK * 4 + 16];
    part_body(smem, blockIdx.x, src, dst, gcur, ebuf);
}

__global__ __launch_bounds__(256) void k_gemm(const float* __restrict__ x,
                                              const float* __restrict__ W1,
                                              unsigned short* __restrict__ h1) {
    __shared__ __align__(16) char smem[49152];
    gemm_body(smem, blockIdx.x, x, W1, h1);
}

// fused: blocks [0,NB_PART) partition edges, rest do the GEMM (independent work,
// latency-bound scatter waves hide under MFMA waves)
__global__ __launch_bounds__(256) void k_pg(const int* __restrict__ src,
                                            const int* __restrict__ dst,
                                            int* __restrict__ gcur,
                                            int2* __restrict__ ebuf,
                                            const float* __restrict__ x,
                                            const float* __restrict__ W1,
                                            unsigned short* __restrict__ h1) {
    __shared__ __align__(16) char smem[49152];
    if (blockIdx.x < NB_PART) part_body(smem, blockIdx.x, src, dst, gcur, ebuf);
    else                      gemm_body(smem, blockIdx.x - NB_PART, x, W1, h1);
}

// per-bucket degree count + scan -> rp, cnt, dinv (256 nodes/block)
__global__ __launch_bounds__(256) void k_csrA(const int2* __restrict__ ebuf,
                                              const int* __restrict__ bbase,
                                              int* __restrict__ rp,
                                              int* __restrict__ cnt,
                                              float* __restrict__ dinv) {
    __shared__ int lcnt[BNODES];
    __shared__ int psum[BNODES];
    int b = blockIdx.x, t = threadIdx.x;
    int node0 = b << BSHIFT;
    lcnt[t] = 0;
    __syncthreads();
    int base = bbase[b], end = bbase[b + 1];
    for (int e = base + t; e < end; e += 256)
        atomicAdd(&lcnt[ebuf[e].y - node0], 1);
    __syncthreads();
    int c = lcnt[t];
    psum[t] = c;
    __syncthreads();
    for (int s = 1; s < 256; s <<= 1) {
        int u = (t >= s) ? psum[t - s] : 0;
        __syncthreads();
        psum[t] += u;
        __syncthreads();
    }
    int node = node0 + t;
    if (node < N_NODES) {
        rp[node] = base + psum[t] - c;
        cnt[node] = c;
        dinv[node] = rsqrtf((float)(c + 1));
    }
}

// per-bucket CSR emit with LDS cursors (single-block-per-region writes)
__global__ __launch_bounds__(256) void k_csrB(const int2* __restrict__ ebuf,
                                              const int* __restrict__ bbase,
                                              const int* __restrict__ rp,
                                              const float* __restrict__ dinv,
                                              int2* __restrict__ csrw) {
    __shared__ int lcur[BNODES];
    __shared__ float ldv[BNODES];
    int b = blockIdx.x, t = threadIdx.x;
    int node0 = b << BSHIFT;
    int base = bbase[b], end = bbase[b + 1];
    int node = node0 + t;
    if (node < N_NODES) { lcur[t] = rp[node] - base; ldv[t] = dinv[node]; }
    __syncthreads();
    int e = base + t;
    for (; e + 256 < end; e += 512) {
        int2 d0 = ebuf[e];
        int2 d1 = ebuf[e + 256];
        int l0 = d0.y - node0, l1 = d1.y - node0;
        float w0 = dinv[d0.x] * ldv[l0];
        float w1 = dinv[d1.x] * ldv[l1];
        int p0 = atomicAdd(&lcur[l0], 1);
        int p1 = atomicAdd(&lcur[l1], 1);
        csrw[base + p0] = make_int2(d0.x, __float_as_int(w0));
        csrw[base + p1] = make_int2(d1.x, __float_as_int(w1));
    }
    if (e < end) {
        int2 d0 = ebuf[e];
        int l0 = d0.y - node0;
        float w0 = dinv[d0.x] * ldv[l0];
        int p0 = atomicAdd(&lcur[l0], 1);
        csrw[base + p0] = make_int2(d0.x, __float_as_int(w0));
    }
}

// ---------------- agg1 + b1 + ReLU + (r @ W2) -> z[N] ----------------

__global__ __launch_bounds__(256) void k_agg1(const unsigned short* __restrict__ h1,
                                              const float* __restrict__ dinv,
                                              const int* __restrict__ rp,
                                              const int* __restrict__ cnt,
                                              const int2* __restrict__ csrw,
                                              const float* __restrict__ b1,
                                              const float* __restrict__ W2,
                                              float* __restrict__ z) {
    int lane = threadIdx.x & 63;
    int wv = threadIdx.x >> 6;
    int g = lane >> 4, tl = lane & 15;
    int i = blockIdx.x * 16 + wv * 4 + g;
    int c0 = tl * 8;
    float di = dinv[i];
    int beg = rp[i], end = beg + cnt[i];
    float a0 = 0.f, a1 = 0.f, a2 = 0.f, a3 = 0.f, a4 = 0.f, a5 = 0.f, a6 = 0.f, a7 = 0.f;
    const unsigned short* hbase = h1 + c0;

    int j = beg;
    for (; j + 2 <= end; j += 2) {
        int2 e0 = csrw[j];
        int2 e1 = csrw[j + 1];
        uint4 v0 = *(const uint4*)(hbase + (size_t)e0.x * DIM);
        uint4 v1 = *(const uint4*)(hbase + (size_t)e1.x * DIM);
        float w0 = __int_as_float(e0.y), w1 = __int_as_float(e1.y);
        a0 = fmaf(bflo(v0.x), w0, a0); a1 = fmaf(bfhi(v0.x), w0, a1);
        a2 = fmaf(bflo(v0.y), w0, a2); a3 = fmaf(bfhi(v0.y), w0, a3);
        a4 = fmaf(bflo(v0.z), w0, a4); a5 = fmaf(bfhi(v0.z), w0, a5);
        a6 = fmaf(bflo(v0.w), w0, a6); a7 = fmaf(bfhi(v0.w), w0, a7);
        a0 = fmaf(bflo(v1.x), w1, a0); a1 = fmaf(bfhi(v1.x), w1, a1);
        a2 = fmaf(bflo(v1.y), w1, a2); a3 = fmaf(bfhi(v1.y), w1, a3);
        a4 = fmaf(bflo(v1.z), w1, a4); a5 = fmaf(bfhi(v1.z), w1, a5);
        a6 = fmaf(bflo(v1.w), w1, a6); a7 = fmaf(bfhi(v1.w), w1, a7);
    }
    if (j < end) {
        int2 e0 = csrw[j];
        uint4 v0 = *(const uint4*)(hbase + (size_t)e0.x * DIM);
        float w0 = __int_as_float(e0.y);
        a0 = fmaf(bflo(v0.x), w0, a0); a1 = fmaf(bfhi(v0.x), w0, a1);
        a2 = fmaf(bflo(v0.y), w0, a2); a3 = fmaf(bfhi(v0.y), w0, a3);
        a4 = fmaf(bflo(v0.z), w0, a4); a5 = fmaf(bfhi(v0.z), w0, a5);
        a6 = fmaf(bflo(v0.w), w0, a6); a7 = fmaf(bfhi(v0.w), w0, a7);
    }

    uint4 vs = *(const uint4*)(hbase + (size_t)i * DIM);
    float sii = di * di;
    float4 bA = *(const float4*)(b1 + c0);
    float4 bB = *(const float4*)(b1 + c0 + 4);
    float4 wA = *(const float4*)(W2 + c0);
    float4 wB = *(const float4*)(W2 + c0 + 4);
    float p = 0.f;
    p += fmaxf(fmaf(bflo(vs.x), sii, a0) + bA.x, 0.f) * wA.x;
    p += fmaxf(fmaf(bfhi(vs.x), sii, a1) + bA.y, 0.f) * wA.y;
    p += fmaxf(fmaf(bflo(vs.y), sii, a2) + bA.z, 0.f) * wA.z;
    p += fmaxf(fmaf(bfhi(vs.y), sii, a3) + bA.w, 0.f) * wA.w;
    p += fmaxf(fmaf(bflo(vs.z), sii, a4) + bB.x, 0.f) * wB.x;
    p += fmaxf(fmaf(bfhi(vs.z), sii, a5) + bB.y, 0.f) * wB.y;
    p += fmaxf(fmaf(bflo(vs.w), sii, a6) + bB.z, 0.f) * wB.z;
    p += fmaxf(fmaf(bfhi(vs.w), sii, a7) + bB.w, 0.f) * wB.w;
#pragma unroll
    for (int off = 8; off >= 1; off >>= 1) p += __shfl_xor(p, off, 64);
    if (tl == 0) z[i] = p;  // b2 added in agg2
}

// ---------------- agg2 ----------------

__global__ __launch_bounds__(256) void k_agg2(const float* __restrict__ zin,
                                              const float* __restrict__ dinv,
                                              const int* __restrict__ rp,
                                              const int* __restrict__ cnt,
                                              const int2* __restrict__ csrw,
                                              const float* __restrict__ b2,
                                              float* __restrict__ out) {
    int i = blockIdx.x * blockDim.x + threadIdx.x;
    if (i >= N_NODES) return;
    float di = dinv[i];
    int beg = rp[i], end = beg + cnt[i];
    float acc = 0.f;
    int j = beg;
    for (; j + 4 <= end; j += 4) {
        int2 e0 = csrw[j], e1 = csrw[j + 1], e2 = csrw[j + 2], e3 = csrw[j + 3];
        float z0 = zin[e0.x], z1 = zin[e1.x], z2 = zin[e2.x], z3 = zin[e3.x];
        acc = fmaf(z0, __int_as_float(e0.y), acc);
        acc = fmaf(z1, __int_as_float(e1.y), acc);
        acc = fmaf(z2, __int_as_float(e2.y), acc);
        acc = fmaf(z3, __int_as_float(e3.y), acc);
    }
    for (; j < end; ++j) {
        int2 e = csrw[j];
        acc = fmaf(zin[e.x], __int_as_float(e.y), acc);
    }
    out[i] = acc + zin[i] * di * di + b2[0];
}

// ---------------- launch ----------------

extern "C" void kernel_launch(void* const* d_in, const int* in_sizes, int n_in,
                              void* d_out, int out_size, void* d_ws, size_t ws_size,
                              hipStream_t stream) {
    const float* x  = (const float*)d_in[0];
    const int*   ei = (const int*)d_in[1];
    const float* W1 = (const float*)d_in[2];
    const float* b1 = (const float*)d_in[3];
    const float* W2 = (const float*)d_in[4];
    const float* b2 = (const float*)d_in[5];
    float* out = (float*)d_out;

    const int* src = ei;
    const int* dst = ei + N_EDGES;

    char* ws = (char*)d_ws;
    size_t o = 0;
    auto take = [&](size_t bytes) { char* p = ws + o; o += (bytes + 255) & ~(size_t)255; return p; };
    int*   cnt   = (int*)take(sizeof(int) * N_NODES);
    int*   rp    = (int*)take(sizeof(int) * N_NODES);
    int*   bcnt  = (int*)take(sizeof(int) * (NBUCK + 1));
    int*   bbase = (int*)take(sizeof(int) * (NBUCK + 1));
    int*   gcur  = (int*)take(sizeof(int) * (NBUCK + 1));
    float* dinv  = (float*)take(sizeof(float) * N_NODES);
    float* z     = (float*)take(sizeof(float) * N_NODES);
    int2*  csrw  = (int2*)take(sizeof(int2) * N_EDGES);
    unsigned short* h1 = (unsigned short*)take(sizeof(unsigned short) * (size_t)N_NODES * DIM);
    size_t base_need = o;
    int2* ebuf_sep = (int2*)take(sizeof(int2) * N_EDGES);
    bool fused = (o <= ws_size);
    int2* ebuf = fused ? ebuf_sep : (int2*)h1;  // fallback: alias h1 (lifetimes disjoint)
    (void)base_need;

    const int NB_N = (N_NODES + 255) / 256;

    k_zero<<<2, 256, 0, stream>>>(bcnt);
    k_bcount<<<NB_PART, 256, 0, stream>>>(dst, bcnt);
    k_bscan<<<1, 512, 0, stream>>>(bcnt, bbase, gcur);
    if (fused) {
        // part ∥ gemm in one dispatch (independent; ebuf un-aliased from h1)
        k_pg<<<NB_PART + GGRID, 256, 0, stream>>>(src, dst, gcur, ebuf, x, W1, h1);
        k_csrA<<<NBUCK, 256, 0, stream>>>(ebuf, bbase, rp, cnt, dinv);
        k_csrB<<<NBUCK, 256, 0, stream>>>(ebuf, bbase, rp, dinv, csrw);
    } else {
        k_part<<<NB_PART, 256, 0, stream>>>(src, dst, gcur, ebuf);
        k_csrA<<<NBUCK, 256, 0, stream>>>(ebuf, bbase, rp, cnt, dinv);
        k_csrB<<<NBUCK, 256, 0, stream>>>(ebuf, bbase, rp, dinv, csrw);
        k_gemm<<<GGRID, 256, 0, stream>>>(x, W1, h1);  // after last ebuf read
    }
    k_agg1<<<N_NODES / 16, 256, 0, stream>>>(h1, dinv, rp, cnt, csrw, b1, W2, z);
    k_agg2<<<NB_N, 256, 0, stream>>>(z, dinv, rp, cnt, csrw, b2, out);
}

// Round 7
// 145.772 us; speedup vs baseline: 2.0948x; 1.1159x over previous
//
#include <hip/hip_runtime.h>

#define N_NODES 100000
#define N_EDGES 1600000
#define DIM 128

#define BSHIFT 8
#define BNODES 256
#define NBUCK 391     // ceil(100000/256)
#define BCAP  4608    // padded bucket capacity (mean 4096, sigma 64, +8 sigma)
#define PCHUNK 4096   // edges per part block
#define NB_PART ((N_EDGES + PCHUNK - 1) / PCHUNK)  // 391

#define GTILES 1563   // ceil(100000/64)
#define GGRID  782

typedef short s16x8 __attribute__((ext_vector_type(8)));
typedef float f32x4 __attribute__((ext_vector_type(4)));

__device__ __forceinline__ unsigned short f2bf(float f) {
    unsigned u = __float_as_uint(f);
    u += 0x7fffu + ((u >> 16) & 1u);   // RNE
    return (unsigned short)(u >> 16);
}
__device__ __forceinline__ float bflo(unsigned u) { return __uint_as_float(u << 16); }
__device__ __forceinline__ float bfhi(unsigned u) { return __uint_as_float(u & 0xffff0000u); }

// ---------------- CSR build (padded buckets: no global count/scan needed) ----------------

__global__ void k_zero(int* __restrict__ gcur) {
    int t = blockIdx.x * blockDim.x + threadIdx.x;
    if (t < NBUCK) gcur[t] = t * BCAP;
}

// ---- partition body (shared by standalone + fused kernels) ----
__device__ __forceinline__ void part_body(char* smem, int bid,
                                          const int* __restrict__ src,
                                          const int* __restrict__ dst,
                                          int* __restrict__ gcur,
                                          int2* __restrict__ ebuf) {
    int* hist = (int*)smem;
    int* gbase = hist + NBUCK;
    int tid = threadIdx.x;
    long e0 = (long)bid * PCHUNK;
    int n = min(PCHUNK, (int)(N_EDGES - e0));
    for (int b = tid; b < NBUCK; b += 256) hist[b] = 0;
    __syncthreads();

    int mys[16], myd[16];
#pragma unroll
    for (int k = 0; k < 16; ++k) {
        int idx = k * 256 + tid;
        if (idx < n) {
            mys[k] = src[e0 + idx];
            myd[k] = dst[e0 + idx];
            atomicAdd(&hist[myd[k] >> BSHIFT], 1);
        } else {
            myd[k] = -1;
        }
    }
    __syncthreads();
    for (int b = tid; b < NBUCK; b += 256) {
        gbase[b] = hist[b] ? atomicAdd(&gcur[b], hist[b]) : 0;
        hist[b] = 0;  // becomes local cursor
    }
    __syncthreads();
#pragma unroll
    for (int k = 0; k < 16; ++k) {
        if (myd[k] >= 0) {
            int b = myd[k] >> BSHIFT;
            int slot = gbase[b] + atomicAdd(&hist[b], 1);
            ebuf[slot] = make_int2(mys[k], myd[k]);
        }
    }
}

// ---- GEMM body: h1(bf16) = x @ W1, bf16 MFMA, swizzled LDS ----
__device__ __forceinline__ void gemm_body(char* smem, int bid,
                                          const float* __restrict__ x,
                                          const float* __restrict__ W1,
                                          unsigned short* __restrict__ h1) {
    unsigned short* Wt = (unsigned short*)smem;           // 32 KB
    int tid = threadIdx.x;
    for (int idx = tid; idx < DIM * DIM; idx += 256) {
        int k = idx >> 7, c = idx & 127;
        Wt[c * 128 + (k ^ ((c & 7) << 3))] = f2bf(W1[idx]);
    }
    __syncthreads();

    int wv = tid >> 6, lane = tid & 63;
    int g = lane >> 4, tl = lane & 15;
    unsigned short* cst = (unsigned short*)(smem + 32768 + wv * 4096);

    for (int tile = bid; tile < GTILES; tile += GGRID) {
        int rb = tile * 64 + wv * 16;
        if (rb >= N_NODES) continue;

        s16x8 afrag[4];
        const float* xrow = x + (size_t)(rb + tl) * DIM + g * 8;
#pragma unroll
        for (int kc = 0; kc < 4; ++kc) {
            float4 p0 = *(const float4*)(xrow + kc * 32);
            float4 p1 = *(const float4*)(xrow + kc * 32 + 4);
            s16x8 a;
            a[0] = (short)f2bf(p0.x); a[1] = (short)f2bf(p0.y);
            a[2] = (short)f2bf(p0.z); a[3] = (short)f2bf(p0.w);
            a[4] = (short)f2bf(p1.x); a[5] = (short)f2bf(p1.y);
            a[6] = (short)f2bf(p1.z); a[7] = (short)f2bf(p1.w);
            afrag[kc] = a;
        }

        f32x4 acc[8];
#pragma unroll
        for (int ct = 0; ct < 8; ++ct) acc[ct] = (f32x4)0.0f;
#pragma unroll
        for (int kc = 0; kc < 4; ++kc) {
#pragma unroll
            for (int ct = 0; ct < 8; ++ct) {
                int crow = ct * 16 + tl;
                int boff = crow * 256 + ((kc * 64 + g * 16) ^ ((crow & 7) << 4));
                s16x8 b = *(const s16x8*)((const char*)Wt + boff);
                acc[ct] = __builtin_amdgcn_mfma_f32_16x16x32_bf16(afrag[kc], b, acc[ct], 0, 0, 0);
            }
        }

#pragma unroll
        for (int ct = 0; ct < 8; ++ct) {
#pragma unroll
            for (int r = 0; r < 4; ++r) {
                float own = acc[ct][r];
                float oth = __shfl_xor(own, 1, 64);
                if ((lane & 1) == 0) {
                    unsigned pk = (unsigned)f2bf(own) | ((unsigned)f2bf(oth) << 16);
                    int row = g * 4 + r;
                    int col = ct * 16 + tl;
                    *(unsigned*)&cst[row * 128 + (col ^ (row << 3))] = pk;
                }
            }
        }
        asm volatile("s_waitcnt lgkmcnt(0)" ::: "memory");

        unsigned short* dstp = h1 + (size_t)rb * DIM;
#pragma unroll
        for (int c = 0; c < 4; ++c) {
            int row = c * 4 + g;
            uint4 v = *(const uint4*)&cst[row * 128 + ((tl ^ row) * 8)];
            *(uint4*)(dstp + c * 512 + lane * 8) = v;
        }
    }
}

// standalone kernels (fallback path when ws is tight)
__global__ __launch_bounds__(256) void k_part(const int* __restrict__ src,
                                              const int* __restrict__ dst,
                                              int* __restrict__ gcur,
                                              int2* __restrict__ ebuf) {
    __shared__ __align__(16) char smem[2 * NBUCK * 4 + 16];
    part_body(smem, blockIdx.x, src, dst, gcur, ebuf);
}

__global__ __launch_bounds__(256) void k_gemm(const float* __restrict__ x,
                                              const float* __restrict__ W1,
                                              unsigned short* __restrict__ h1) {
    __shared__ __align__(16) char smem[49152];
    gemm_body(smem, blockIdx.x, x, W1, h1);
}

// fused: blocks [0,NB_PART) partition edges, rest do the GEMM
__global__ __launch_bounds__(256) void k_pg(const int* __restrict__ src,
                                            const int* __restrict__ dst,
                                            int* __restrict__ gcur,
                                            int2* __restrict__ ebuf,
                                            const float* __restrict__ x,
                                            const float* __restrict__ W1,
                                            unsigned short* __restrict__ h1) {
    __shared__ __align__(16) char smem[49152];
    if (blockIdx.x < NB_PART) part_body(smem, blockIdx.x, src, dst, gcur, ebuf);
    else                      gemm_body(smem, blockIdx.x - NB_PART, x, W1, h1);
}

// per-bucket degree count + scan -> rp, cnt, dinv (256 nodes/block)
__global__ __launch_bounds__(256) void k_csrA(const int2* __restrict__ ebuf,
                                              const int* __restrict__ gcur,
                                              int* __restrict__ rp,
                                              int* __restrict__ cnt,
                                              float* __restrict__ dinv) {
    __shared__ int lcnt[BNODES];
    __shared__ int psum[BNODES];
    int b = blockIdx.x, t = threadIdx.x;
    int node0 = b << BSHIFT;
    lcnt[t] = 0;
    __syncthreads();
    int base = b * BCAP, end = gcur[b];
    for (int e = base + t; e < end; e += 256)
        atomicAdd(&lcnt[ebuf[e].y - node0], 1);
    __syncthreads();
    int c = lcnt[t];
    psum[t] = c;
    __syncthreads();
    for (int s = 1; s < 256; s <<= 1) {
        int u = (t >= s) ? psum[t - s] : 0;
        __syncthreads();
        psum[t] += u;
        __syncthreads();
    }
    int node = node0 + t;
    if (node < N_NODES) {
        rp[node] = base + psum[t] - c;
        cnt[node] = c;
        dinv[node] = rsqrtf((float)(c + 1));
    }
}

// per-bucket CSR emit with LDS cursors (single-block-per-region writes)
__global__ __launch_bounds__(256) void k_csrB(const int2* __restrict__ ebuf,
                                              const int* __restrict__ gcur,
                                              const int* __restrict__ rp,
                                              const float* __restrict__ dinv,
                                              int2* __restrict__ csrw) {
    __shared__ int lcur[BNODES];
    __shared__ float ldv[BNODES];
    int b = blockIdx.x, t = threadIdx.x;
    int node0 = b << BSHIFT;
    int base = b * BCAP, end = gcur[b];
    int node = node0 + t;
    if (node < N_NODES) { lcur[t] = rp[node] - base; ldv[t] = dinv[node]; }
    __syncthreads();
    int e = base + t;
    for (; e + 256 < end; e += 512) {
        int2 d0 = ebuf[e];
        int2 d1 = ebuf[e + 256];
        int l0 = d0.y - node0, l1 = d1.y - node0;
        float w0 = dinv[d0.x] * ldv[l0];
        float w1 = dinv[d1.x] * ldv[l1];
        int p0 = atomicAdd(&lcur[l0], 1);
        int p1 = atomicAdd(&lcur[l1], 1);
        csrw[base + p0] = make_int2(d0.x, __float_as_int(w0));
        csrw[base + p1] = make_int2(d1.x, __float_as_int(w1));
    }
    if (e < end) {
        int2 d0 = ebuf[e];
        int l0 = d0.y - node0;
        float w0 = dinv[d0.x] * ldv[l0];
        int p0 = atomicAdd(&lcur[l0], 1);
        csrw[base + p0] = make_int2(d0.x, __float_as_int(w0));
    }
}

// ---------------- agg1 + b1 + ReLU + (r @ W2) -> z[N] ----------------
// 16-lane group per node; unroll x4: 4 csrw reads then 4 independent gathers in flight

__global__ __launch_bounds__(256) void k_agg1(const unsigned short* __restrict__ h1,
                                              const float* __restrict__ dinv,
                                              const int* __restrict__ rp,
                                              const int* __restrict__ cnt,
                                              const int2* __restrict__ csrw,
                                              const float* __restrict__ b1,
                                              const float* __restrict__ W2,
                                              float* __restrict__ z) {
    int lane = threadIdx.x & 63;
    int wv = threadIdx.x >> 6;
    int g = lane >> 4, tl = lane & 15;
    int i = blockIdx.x * 16 + wv * 4 + g;
    int c0 = tl * 8;
    float di = dinv[i];
    int beg = rp[i], end = beg + cnt[i];
    float a0 = 0.f, a1 = 0.f, a2 = 0.f, a3 = 0.f, a4 = 0.f, a5 = 0.f, a6 = 0.f, a7 = 0.f;
    const unsigned short* hbase = h1 + c0;

    int j = beg;
    for (; j + 4 <= end; j += 4) {
        int2 e0 = csrw[j];
        int2 e1 = csrw[j + 1];
        int2 e2 = csrw[j + 2];
        int2 e3 = csrw[j + 3];
        uint4 v0 = *(const uint4*)(hbase + (size_t)e0.x * DIM);
        uint4 v1 = *(const uint4*)(hbase + (size_t)e1.x * DIM);
        uint4 v2 = *(const uint4*)(hbase + (size_t)e2.x * DIM);
        uint4 v3 = *(const uint4*)(hbase + (size_t)e3.x * DIM);
        float w0 = __int_as_float(e0.y), w1 = __int_as_float(e1.y);
        float w2 = __int_as_float(e2.y), w3 = __int_as_float(e3.y);
        a0 = fmaf(bflo(v0.x), w0, a0); a1 = fmaf(bfhi(v0.x), w0, a1);
        a2 = fmaf(bflo(v0.y), w0, a2); a3 = fmaf(bfhi(v0.y), w0, a3);
        a4 = fmaf(bflo(v0.z), w0, a4); a5 = fmaf(bfhi(v0.z), w0, a5);
        a6 = fmaf(bflo(v0.w), w0, a6); a7 = fmaf(bfhi(v0.w), w0, a7);
        a0 = fmaf(bflo(v1.x), w1, a0); a1 = fmaf(bfhi(v1.x), w1, a1);
        a2 = fmaf(bflo(v1.y), w1, a2); a3 = fmaf(bfhi(v1.y), w1, a3);
        a4 = fmaf(bflo(v1.z), w1, a4); a5 = fmaf(bfhi(v1.z), w1, a5);
        a6 = fmaf(bflo(v1.w), w1, a6); a7 = fmaf(bfhi(v1.w), w1, a7);
        a0 = fmaf(bflo(v2.x), w2, a0); a1 = fmaf(bfhi(v2.x), w2, a1);
        a2 = fmaf(bflo(v2.y), w2, a2); a3 = fmaf(bfhi(v2.y), w2, a3);
        a4 = fmaf(bflo(v2.z), w2, a4); a5 = fmaf(bfhi(v2.z), w2, a5);
        a6 = fmaf(bflo(v2.w), w2, a6); a7 = fmaf(bfhi(v2.w), w2, a7);
        a0 = fmaf(bflo(v3.x), w3, a0); a1 = fmaf(bfhi(v3.x), w3, a1);
        a2 = fmaf(bflo(v3.y), w3, a2); a3 = fmaf(bfhi(v3.y), w3, a3);
        a4 = fmaf(bflo(v3.z), w3, a4); a5 = fmaf(bfhi(v3.z), w3, a5);
        a6 = fmaf(bflo(v3.w), w3, a6); a7 = fmaf(bfhi(v3.w), w3, a7);
    }
    for (; j < end; ++j) {
        int2 e0 = csrw[j];
        uint4 v0 = *(const uint4*)(hbase + (size_t)e0.x * DIM);
        float w0 = __int_as_float(e0.y);
        a0 = fmaf(bflo(v0.x), w0, a0); a1 = fmaf(bfhi(v0.x), w0, a1);
        a2 = fmaf(bflo(v0.y), w0, a2); a3 = fmaf(bfhi(v0.y), w0, a3);
        a4 = fmaf(bflo(v0.z), w0, a4); a5 = fmaf(bfhi(v0.z), w0, a5);
        a6 = fmaf(bflo(v0.w), w0, a6); a7 = fmaf(bfhi(v0.w), w0, a7);
    }

    uint4 vs = *(const uint4*)(hbase + (size_t)i * DIM);
    float sii = di * di;
    float4 bA = *(const float4*)(b1 + c0);
    float4 bB = *(const float4*)(b1 + c0 + 4);
    float4 wA = *(const float4*)(W2 + c0);
    float4 wB = *(const float4*)(W2 + c0 + 4);
    float p = 0.f;
    p += fmaxf(fmaf(bflo(vs.x), sii, a0) + bA.x, 0.f) * wA.x;
    p += fmaxf(fmaf(bfhi(vs.x), sii, a1) + bA.y, 0.f) * wA.y;
    p += fmaxf(fmaf(bflo(vs.y), sii, a2) + bA.z, 0.f) * wA.z;
    p += fmaxf(fmaf(bfhi(vs.y), sii, a3) + bA.w, 0.f) * wA.w;
    p += fmaxf(fmaf(bflo(vs.z), sii, a4) + bB.x, 0.f) * wB.x;
    p += fmaxf(fmaf(bfhi(vs.z), sii, a5) + bB.y, 0.f) * wB.y;
    p += fmaxf(fmaf(bflo(vs.w), sii, a6) + bB.z, 0.f) * wB.z;
    p += fmaxf(fmaf(bfhi(vs.w), sii, a7) + bB.w, 0.f) * wB.w;
#pragma unroll
    for (int off = 8; off >= 1; off >>= 1) p += __shfl_xor(p, off, 64);
    if (tl == 0) z[i] = p;  // b2 added in agg2
}

// ---------------- agg2 ----------------

__global__ __launch_bounds__(256) void k_agg2(const float* __restrict__ zin,
                                              const float* __restrict__ dinv,
                                              const int* __restrict__ rp,
                                              const int* __restrict__ cnt,
                                              const int2* __restrict__ csrw,
                                              const float* __restrict__ b2,
                                              float* __restrict__ out) {
    int i = blockIdx.x * blockDim.x + threadIdx.x;
    if (i >= N_NODES) return;
    float di = dinv[i];
    int beg = rp[i], end = beg + cnt[i];
    float acc = 0.f;
    int j = beg;
    for (; j + 4 <= end; j += 4) {
        int2 e0 = csrw[j], e1 = csrw[j + 1], e2 = csrw[j + 2], e3 = csrw[j + 3];
        float z0 = zin[e0.x], z1 = zin[e1.x], z2 = zin[e2.x], z3 = zin[e3.x];
        acc = fmaf(z0, __int_as_float(e0.y), acc);
        acc = fmaf(z1, __int_as_float(e1.y), acc);
        acc = fmaf(z2, __int_as_float(e2.y), acc);
        acc = fmaf(z3, __int_as_float(e3.y), acc);
    }
    for (; j < end; ++j) {
        int2 e = csrw[j];
        acc = fmaf(zin[e.x], __int_as_float(e.y), acc);
    }
    out[i] = acc + zin[i] * di * di + b2[0];
}

// ---------------- launch ----------------

extern "C" void kernel_launch(void* const* d_in, const int* in_sizes, int n_in,
                              void* d_out, int out_size, void* d_ws, size_t ws_size,
                              hipStream_t stream) {
    const float* x  = (const float*)d_in[0];
    const int*   ei = (const int*)d_in[1];
    const float* W1 = (const float*)d_in[2];
    const float* b1 = (const float*)d_in[3];
    const float* W2 = (const float*)d_in[4];
    const float* b2 = (const float*)d_in[5];
    float* out = (float*)d_out;

    const int* src = ei;
    const int* dst = ei + N_EDGES;

    char* ws = (char*)d_ws;
    size_t o = 0;
    auto take = [&](size_t bytes) { char* p = ws + o; o += (bytes + 255) & ~(size_t)255; return p; };
    int*   cnt   = (int*)take(sizeof(int) * N_NODES);
    int*   rp    = (int*)take(sizeof(int) * N_NODES);
    int*   gcur  = (int*)take(sizeof(int) * (NBUCK + 1));
    float* dinv  = (float*)take(sizeof(float) * N_NODES);
    float* z     = (float*)take(sizeof(float) * N_NODES);
    int2*  csrw  = (int2*)take(sizeof(int2) * (size_t)NBUCK * BCAP);
    unsigned short* h1 = (unsigned short*)take(sizeof(unsigned short) * (size_t)N_NODES * DIM);
    int2* ebuf_sep = (int2*)take(sizeof(int2) * (size_t)NBUCK * BCAP);
    bool fused = (o <= ws_size);
    int2* ebuf = fused ? ebuf_sep : (int2*)h1;  // fallback: alias h1 (lifetimes disjoint)

    const int NB_N = (N_NODES + 255) / 256;

    k_zero<<<2, 256, 0, stream>>>(gcur);
    if (fused) {
        k_pg<<<NB_PART + GGRID, 256, 0, stream>>>(src, dst, gcur, ebuf, x, W1, h1);
        k_csrA<<<NBUCK, 256, 0, stream>>>(ebuf, gcur, rp, cnt, dinv);
        k_csrB<<<NBUCK, 256, 0, stream>>>(ebuf, gcur, rp, dinv, csrw);
    } else {
        k_part<<<NB_PART, 256, 0, stream>>>(src, dst, gcur, ebuf);
        k_csrA<<<NBUCK, 256, 0, stream>>>(ebuf, gcur, rp, cnt, dinv);
        k_csrB<<<NBUCK, 256, 0, stream>>>(ebuf, gcur, rp, dinv, csrw);
        k_gemm<<<GGRID, 256, 0, stream>>>(x, W1, h1);  // after last ebuf read
    }
    k_agg1<<<N_NODES / 16, 256, 0, stream>>>(h1, dinv, rp, cnt, csrw, b1, W2, z);
    k_agg2<<<NB_N, 256, 0, stream>>>(z, dinv, rp, cnt, csrw, b2, out);
}